// Round 1
// baseline (468.387 us; speedup 1.0000x reference)
//
#include <hip/hip_runtime.h>
#include <math.h>

// Shift-GCN fused block for N=64,T=256,V=25,C=D=64 (fp32).
// shift_in(w,c)  = ((w+c)%25)*64 + c          (derived from (64w+65c) mod 1600)
// shift_out inverse: lin (w,d) -> gathered ((w+d)%25, d)
// Linear_bias cancels in BatchNorm (constant per column) -> ignored.
//
// ws layout (floats):
//   [0,1600)    maskt = tanh(Feature_Mask)+1
//   [1600,3200) column sums (lin space)
//   [3200,4800) column sum-of-squares
//   [4800,6400) mul[q]  = gamma[si(q)] * istd[q]
//   [6400,8000) add[q]  = beta[si(q)] - mean[q]*mul[q]

#define RPB 16      // rows per block
#define LDW 68      // padded LDS row stride (floats): odd-bank shift, 16B aligned

__global__ void k_prep(const float* __restrict__ mask, float* __restrict__ ws) {
  int i = blockIdx.x * 256 + threadIdx.x;
  if (i < 1600) ws[i] = tanhf(mask[i]) + 1.0f;
  if (i < 3200) ws[1600 + i] = 0.0f;   // zero sum + sumsq regions
}

__global__ void k_finalize(const float* __restrict__ gamma,
                           const float* __restrict__ beta,
                           float* __restrict__ ws) {
  int q = blockIdx.x * 256 + threadIdx.x;
  if (q >= 1600) return;
  const float inv = 1.0f / 16384.0f;
  float mean = ws[1600 + q] * inv;
  float var  = ws[3200 + q] * inv - mean * mean;   // biased var (ddof=0)
  float istd = rsqrtf(var + 1e-5f);
  int w = q >> 6, d = q & 63;
  int wp = (w + d) % 25;
  int p  = wp * 64 + d;                 // gathered-space index
  float mul = gamma[p] * istd;
  ws[4800 + q] = mul;
  ws[6400 + q] = beta[p] - mean * mul;
}

template<int PASS>
__launch_bounds__(256, 2)
__global__ void k_main(const float* __restrict__ x0,
                       const float* __restrict__ Wg,
                       float* ws,                    // no restrict: aliased regions
                       float* __restrict__ out) {
  __shared__ float s_W[4096];        // W[c][d], stride 64
  __shared__ float s_maskt[1600];
  __shared__ float s_raw[2][1700];   // raw x0 rows, [w*LDW + c]
  __shared__ float s_xy[2][1904];    // masked/gathered xm (28 rows); pass2 reused as y tile [d*28+wp]
  __shared__ float s_a[1600];        // pass1: sum partials | pass2: mul
  __shared__ float s_b[1600];        // pass1: sq partials  | pass2: add

  const int tid = threadIdx.x;

  for (int i = tid; i < 4096; i += 256) s_W[i] = Wg[i];
  for (int i = tid; i < 1600; i += 256) s_maskt[i] = ws[i];
  if constexpr (PASS == 1) {
    for (int i = tid; i < 1600; i += 256) { s_a[i] = 0.f; s_b[i] = 0.f; }
  } else {
    for (int i = tid; i < 1600; i += 256) { s_a[i] = ws[4800 + i]; s_b[i] = ws[6400 + i]; }
  }

  // GEMM thread mapping: 2 rows x (7 wtiles x 16 dtiles) = 224 active threads
  const bool active = tid < 224;
  const int rs = tid / 112;
  const int rr = tid % 112;
  const int d0 = (rr % 16) * 4;
  const int w0 = (rr / 16) * 4;

  float ssum[16], ssq[16];
  if constexpr (PASS == 1) {
    #pragma unroll
    for (int k = 0; k < 16; ++k) { ssum[k] = 0.f; ssq[k] = 0.f; }
  }

  const int row_base = blockIdx.x * RPB;   // 16 consecutive t within one n
  const int n  = row_base >> 8;
  const int t0 = row_base & 255;

  __syncthreads();

  for (int rp = 0; rp < RPB; rp += 2) {
    // ---- stage 2 raw rows (coalesced float4) ----
    const float* xrow = x0 + (size_t)(row_base + rp) * 1600;
    for (int i4 = tid; i4 < 800; i4 += 256) {
      float4 v = ((const float4*)xrow)[i4];
      int p4 = i4 * 4;
      int r2 = (p4 >= 1600) ? 1 : 0;
      int p  = p4 - r2 * 1600;
      *(float4*)&s_raw[r2][(p >> 6) * LDW + (p & 63)] = v;
    }
    __syncthreads();

    // ---- shift-in gather + mask into xm (rows 25..27 zero-padded) ----
    for (int i = tid; i < 3584; i += 256) {
      int r2 = (i >= 1792) ? 1 : 0;
      int p  = i - r2 * 1792;
      int w = p >> 6, c = p & 63;
      float v = 0.f;
      if (w < 25) v = s_raw[r2][((w + c) % 25) * LDW + c] * s_maskt[w * 64 + c];
      s_xy[r2][w * LDW + c] = v;
    }
    __syncthreads();

    // ---- 4w x 4d x (4c-unrolled) register-tiled GEMM ----
    float acc[4][4];
    if (active) {
      #pragma unroll
      for (int i = 0; i < 4; ++i)
        #pragma unroll
        for (int j = 0; j < 4; ++j) acc[i][j] = 0.f;
      for (int c = 0; c < 64; c += 4) {
        float A[4][4], B[4][4];
        #pragma unroll
        for (int i = 0; i < 4; ++i)
          *(float4*)A[i] = *(const float4*)&s_xy[rs][(w0 + i) * LDW + c];
        #pragma unroll
        for (int k = 0; k < 4; ++k)
          *(float4*)B[k] = *(const float4*)&s_W[(c + k) * 64 + d0];
        #pragma unroll
        for (int i = 0; i < 4; ++i)
          #pragma unroll
          for (int j = 0; j < 4; ++j)
            #pragma unroll
            for (int k = 0; k < 4; ++k)
              acc[i][j] = fmaf(A[i][k], B[k][j], acc[i][j]);
      }
    }

    if constexpr (PASS == 1) {
      if (active) {
        #pragma unroll
        for (int i = 0; i < 4; ++i) {
          if (w0 + i < 25) {
            #pragma unroll
            for (int j = 0; j < 4; ++j) {
              ssum[i * 4 + j] += acc[i][j];
              ssq [i * 4 + j]  = fmaf(acc[i][j], acc[i][j], ssq[i * 4 + j]);
            }
          }
        }
      }
      __syncthreads();   // GEMM reads done before next stage overwrites LDS
    } else {
      __syncthreads();   // all xm reads done: safe to reuse s_xy as y tile
      if (active) {
        #pragma unroll
        for (int i = 0; i < 4; ++i) {
          int w = w0 + i;
          if (w < 25) {
            #pragma unroll
            for (int j = 0; j < 4; ++j) {
              int d = d0 + j;
              int q = w * 64 + d;
              int wp = (w + d) % 25;               // shift-out target node
              float v = fmaf(acc[i][j], s_a[q], s_b[q]);
              v += s_raw[rs][wp * LDW + d];        // residual x0[n,t,wp,d]
              v = fmaxf(v, 0.f);
              s_xy[rs][d * 28 + wp] = v;
            }
          }
        }
      }
      __syncthreads();
      // ---- transposed store: contiguous 50-float runs per d ----
      for (int i = tid; i < 3200; i += 256) {
        int d   = i / 50;
        int rem = i - d * 50;
        int r2  = rem / 25;
        int wp  = rem - r2 * 25;
        int t   = t0 + rp + r2;
        out[(size_t)(((n * 64 + d) * 256 + t) * 25 + wp)] = s_xy[r2][d * 28 + wp];
      }
      __syncthreads();
    }
  }

  if constexpr (PASS == 1) {
    // combine per-thread stats -> LDS -> one global atomic per column per block
    if (active) {
      #pragma unroll
      for (int i = 0; i < 4; ++i) {
        int w = w0 + i;
        if (w < 25) {
          #pragma unroll
          for (int j = 0; j < 4; ++j) {
            int q = w * 64 + d0 + j;
            atomicAdd(&s_a[q], ssum[i * 4 + j]);
            atomicAdd(&s_b[q], ssq [i * 4 + j]);
          }
        }
      }
    }
    __syncthreads();
    for (int i = tid; i < 1600; i += 256) {
      atomicAdd(&ws[1600 + i], s_a[i]);
      atomicAdd(&ws[3200 + i], s_b[i]);
    }
  }
}

extern "C" void kernel_launch(void* const* d_in, const int* in_sizes, int n_in,
                              void* d_out, int out_size, void* d_ws, size_t ws_size,
                              hipStream_t stream) {
  const float* x0    = (const float*)d_in[0];
  const float* W     = (const float*)d_in[1];
  // d_in[2] Linear_bias: cancels in BN, ignored
  const float* mask  = (const float*)d_in[3];
  const float* gamma = (const float*)d_in[4];
  const float* beta  = (const float*)d_in[5];
  // d_in[6], d_in[7] shift indices: computed analytically, ignored
  float* ws  = (float*)d_ws;
  float* out = (float*)d_out;

  k_prep    <<<13,   256, 0, stream>>>(mask, ws);
  k_main<1> <<<1024, 256, 0, stream>>>(x0, W, ws, out);
  k_finalize<<<7,    256, 0, stream>>>(gamma, beta, ws);
  k_main<2> <<<1024, 256, 0, stream>>>(x0, W, ws, out);
}

// Round 2
// 407.645 us; speedup vs baseline: 1.1490x; 1.1490x over previous
//
#include <hip/hip_runtime.h>
#include <math.h>

// Shift-GCN fused block, N=64,T=256,V=25,C=D=64 (fp32).
// shift_in:  gathered(w,c)  = raw((w+c)%25, c)
// shift_out: lin (w,d) -> output node wp=(w+d)%25
// Linear_bias cancels in BatchNorm -> ignored.
//
// ws layout (floats):
//   [0,1600)    maskr = tanh(Feature_Mask)+1, permuted to RAW-space layout:
//               maskr[w'*64+c] = maskt[(w'-c)%25][c]
//   [1600,3200) column sums (lin space)
//   [3200,4800) column sum-of-squares
//   [4800,6400) mul[q] = gamma[out(q)] * istd[q]
//   [6400,8000) add[q] = beta[out(q)] - mean[q]*mul[q]

#define LDW 68   // padded LDS row stride (floats)

__global__ void k_prep(const float* __restrict__ mask, float* __restrict__ ws) {
  int i = blockIdx.x * 256 + threadIdx.x;
  if (i < 1600) {
    int w = i >> 6, c = i & 63;
    int wr = (w + c) % 25;                     // raw row this gathered (w,c) reads
    ws[wr * 64 + c] = tanhf(mask[i]) + 1.0f;   // store mask in raw-space layout
  }
  if (i < 3200) ws[1600 + i] = 0.0f;           // zero sum + sumsq
}

__global__ void k_finalize(const float* __restrict__ gamma,
                           const float* __restrict__ beta,
                           float* __restrict__ ws) {
  int q = blockIdx.x * 256 + threadIdx.x;
  if (q >= 1600) return;
  const float inv = 1.0f / 16384.0f;
  float mean = ws[1600 + q] * inv;
  float var  = ws[3200 + q] * inv - mean * mean;   // biased var
  float istd = rsqrtf(var + 1e-5f);
  int w = q >> 6, d = q & 63;
  int wp = (w + d) % 25;
  int p  = wp * 64 + d;                 // output-space column index
  float mul = gamma[p] * istd;
  ws[4800 + q] = mul;
  ws[6400 + q] = beta[p] - mean * mul;
}

template<int PASS>
__launch_bounds__(256, 4)
__global__ void k_main(const float* __restrict__ x0,
                       const float* __restrict__ Wg,
                       float* ws,                    // aliased regions, no restrict
                       float* __restrict__ out) {
  __shared__ float s_W[4096];        // W[c][d]
  __shared__ float s_maskr[1600];    // raw-space mask
  __shared__ float s_xy[2][1904];    // gathered+masked xm [w*LDW+c]; pass2 reuses as y tile [d*28+wp]; pass1 end reuses as stat-combine

  const int tid = threadIdx.x;

  for (int i = tid; i < 4096; i += 256) s_W[i] = Wg[i];
  for (int i = tid; i < 1600; i += 256) s_maskr[i] = ws[i];

  // GEMM mapping: 2 row-sets x (7 w-tiles x 16 d-tiles) = 224 active threads
  const bool active = tid < 224;
  const int rs = tid / 112;
  const int rr = tid % 112;
  const int d0 = (rr % 16) * 4;
  const int w0 = (rr / 16) * 4;

  float cmul[16], cadd[16];
  if constexpr (PASS == 2) {
    if (active) {
      #pragma unroll
      for (int i = 0; i < 4; ++i)
        #pragma unroll
        for (int j = 0; j < 4; ++j) {
          int q = (w0 + i) * 64 + d0 + j;
          cmul[i * 4 + j] = ws[4800 + q];
          cadd[i * 4 + j] = ws[6400 + q];
        }
    }
  }

  float ssum[16], ssq[16];
  if constexpr (PASS == 1) {
    #pragma unroll
    for (int k = 0; k < 16; ++k) { ssum[k] = 0.f; ssq[k] = 0.f; }
  }

  const int row_base = blockIdx.x * 16;
  const int n  = row_base >> 8;
  const int t0 = row_base & 255;

  __syncthreads();

  for (int rp = 0; rp < 16; rp += 2) {
    const float* xrow = x0 + (size_t)(row_base + rp) * 1600;

    // ---- merged stage + shift-in gather + mask (scatter into s_xy) ----
    for (int i4 = tid; i4 < 800; i4 += 256) {
      float4 v = ((const float4*)xrow)[i4];
      int r2 = (i4 >= 400) ? 1 : 0;
      int p4 = (i4 - r2 * 400) * 4;          // raw-space float offset
      float4 m = *(const float4*)&s_maskr[p4];
      int wr = p4 >> 6;
      int c  = p4 & 63;
      float va[4] = {v.x, v.y, v.z, v.w};
      float ma[4] = {m.x, m.y, m.z, m.w};
      int base = wr + 75 - c;                // (wr - c - j) mod 25, kept positive
      #pragma unroll
      for (int j = 0; j < 4; ++j) {
        int w = (base - j) % 25;
        s_xy[r2][w * LDW + c + j] = va[j] * ma[j];
      }
    }
    __syncthreads();

    // ---- 4w x 4d x 4c register-tiled GEMM ----
    float acc[4][4];
    if (active) {
      #pragma unroll
      for (int i = 0; i < 4; ++i)
        #pragma unroll
        for (int j = 0; j < 4; ++j) acc[i][j] = 0.f;
      for (int c = 0; c < 64; c += 4) {
        float A[4][4], B[4][4];
        #pragma unroll
        for (int i = 0; i < 4; ++i)
          *(float4*)A[i] = *(const float4*)&s_xy[rs][(w0 + i) * LDW + c];
        #pragma unroll
        for (int k = 0; k < 4; ++k)
          *(float4*)B[k] = *(const float4*)&s_W[(c + k) * 64 + d0];
        #pragma unroll
        for (int i = 0; i < 4; ++i)
          #pragma unroll
          for (int j = 0; j < 4; ++j)
            #pragma unroll
            for (int k = 0; k < 4; ++k)
              acc[i][j] = fmaf(A[i][k], B[k][j], acc[i][j]);
      }
    }

    if constexpr (PASS == 1) {
      if (active) {
        #pragma unroll
        for (int i = 0; i < 4; ++i) {
          if (w0 + i < 25) {
            #pragma unroll
            for (int j = 0; j < 4; ++j) {
              ssum[i * 4 + j] += acc[i][j];
              ssq [i * 4 + j]  = fmaf(acc[i][j], acc[i][j], ssq[i * 4 + j]);
            }
          }
        }
      }
      __syncthreads();   // GEMM reads done before next scatter overwrites s_xy
    } else {
      __syncthreads();   // all xm reads done: reuse s_xy as y tile
      if (active) {
        const float* xres = xrow + rs * 1600;   // residual row (L1/L2-warm)
        #pragma unroll
        for (int i = 0; i < 4; ++i) {
          int w = w0 + i;
          if (w < 25) {
            #pragma unroll
            for (int j = 0; j < 4; ++j) {
              int d = d0 + j;
              int k = i * 4 + j;
              int wp = (w + d) % 25;             // shift-out target node
              float vv = fmaf(acc[i][j], cmul[k], cadd[k]) + xres[wp * 64 + d];
              s_xy[rs][d * 28 + wp] = fmaxf(vv, 0.f);
            }
          }
        }
      }
      __syncthreads();
      // ---- transposed store: contiguous 25-float runs per (d,t) ----
      for (int i = tid; i < 3200; i += 256) {
        int d   = i / 50;
        int rem = i - d * 50;
        int r2  = rem / 25;
        int wp  = rem - r2 * 25;
        int t   = t0 + rp + r2;
        out[(size_t)(((n * 64 + d) * 256 + t) * 25 + wp)] = s_xy[r2][d * 28 + wp];
      }
      __syncthreads();
    }
  }

  if constexpr (PASS == 1) {
    // combine per-thread stats in reused s_xy, then one atomic per column per block
    float* comb = &s_xy[0][0];   // 3808 floats available, need 3200
    for (int i = tid; i < 3200; i += 256) comb[i] = 0.f;
    __syncthreads();
    if (active) {
      #pragma unroll
      for (int i = 0; i < 4; ++i) {
        int w = w0 + i;
        if (w < 25) {
          #pragma unroll
          for (int j = 0; j < 4; ++j) {
            int q = w * 64 + d0 + j;
            atomicAdd(&comb[q],        ssum[i * 4 + j]);
            atomicAdd(&comb[1600 + q], ssq [i * 4 + j]);
          }
        }
      }
    }
    __syncthreads();
    for (int i = tid; i < 3200; i += 256) {
      atomicAdd(&ws[1600 + i], comb[i]);
    }
  }
}

extern "C" void kernel_launch(void* const* d_in, const int* in_sizes, int n_in,
                              void* d_out, int out_size, void* d_ws, size_t ws_size,
                              hipStream_t stream) {
  const float* x0    = (const float*)d_in[0];
  const float* W     = (const float*)d_in[1];
  // d_in[2] Linear_bias: cancels in BN, ignored
  const float* mask  = (const float*)d_in[3];
  const float* gamma = (const float*)d_in[4];
  const float* beta  = (const float*)d_in[5];
  // d_in[6], d_in[7] shift indices: computed analytically, ignored
  float* ws  = (float*)d_ws;
  float* out = (float*)d_out;

  k_prep    <<<13,   256, 0, stream>>>(mask, ws);
  k_main<1> <<<1024, 256, 0, stream>>>(x0, W, ws, out);
  k_finalize<<<7,    256, 0, stream>>>(gamma, beta, ws);
  k_main<2> <<<1024, 256, 0, stream>>>(x0, W, ws, out);
}

// Round 4
// 346.683 us; speedup vs baseline: 1.3511x; 1.1758x over previous
//
#include <hip/hip_runtime.h>
#include <math.h>

// Shift-GCN fused block, N=64,T=256,V=25,C=D=64. bf16-MFMA GEMM, fp32 everything else.
// shift_in:  gathered(w,c) = raw((w+c)%25, c)
// shift_out: lin (w,d) -> output node wp=(w+d)%25
// Linear_bias cancels in BatchNorm -> ignored.
//
// ws layout (floats):
//   [0,800)     maskr: 1600 bf16 (ushort) in RAW-space layout: maskm[wr*64+c] = bf16(tanh(FM[(wr-c)%25][c])+1)
//   [1600,3200) column sums (lin space q = w*64+d)
//   [3200,4800) column sum-of-squares
//   [4800,6400) mul[q] = gamma[out(q)] * istd[q]
//   [6400,8000) add[q] = beta[out(q)] - mean[q]*mul[q]

typedef __attribute__((ext_vector_type(8))) short bf16x8;
typedef __attribute__((ext_vector_type(4))) float f32x4;

__device__ __forceinline__ ushort f2bf(float f) {
  uint u; __builtin_memcpy(&u, &f, 4);
  u += 0x7fffu + ((u >> 16) & 1u);       // RNE
  return (ushort)(u >> 16);
}
__device__ __forceinline__ float bf2f(ushort b) {
  uint u = ((uint)b) << 16; float f; __builtin_memcpy(&f, &u, 4); return f;
}

__global__ void k_prep(const float* __restrict__ mask, float* __restrict__ ws) {
  int i = blockIdx.x * 256 + threadIdx.x;
  if (i < 1600) {
    int w = i >> 6, c = i & 63;
    int wr = (w + c) % 25;                    // raw row feeding gathered (w,c)
    ((ushort*)ws)[wr * 64 + c] = f2bf(tanhf(mask[i]) + 1.0f);
  }
  if (i < 3200) ws[1600 + i] = 0.0f;
}

__global__ void k_finalize(const float* __restrict__ gamma,
                           const float* __restrict__ beta,
                           float* __restrict__ ws) {
  int q = blockIdx.x * 256 + threadIdx.x;
  if (q >= 1600) return;
  const float inv = 1.0f / 16384.0f;
  float mean = ws[1600 + q] * inv;
  float var  = ws[3200 + q] * inv - mean * mean;
  float istd = rsqrtf(var + 1e-5f);
  int w = q >> 6, d = q & 63;
  int p = ((w + d) % 25) * 64 + d;            // output-space column
  float mul = gamma[p] * istd;
  ws[4800 + q] = mul;
  ws[6400 + q] = beta[p] - mean * mul;
}

template<int PASS>
__launch_bounds__(256, 4)
__global__ void k_main(const float* __restrict__ x0,
                       const float* __restrict__ Wg,
                       float* ws,
                       float* __restrict__ out) {
  __shared__ __align__(8)  ushort s_maskm[1600];            // bf16 raw-space mask
  __shared__ __align__(16) ushort s_A[4096];                // [64 rows][64 c] bf16, XOR-swizzled
  __shared__ float s_raw[PASS == 2 ? 3400 : 4];             // [2][25*68] fp32 raw rows
  __shared__ float s_aux[3200];                             // pass1: stat combine | pass2: y tile [d][50]

  const int tid = threadIdx.x;
  const int lr  = tid & 63;      // lane
  const int wid = tid >> 6;      // wave 0..3

  // ---- one-time setup ----
  for (int i = tid; i < 800; i += 256)
    ((uint*)s_maskm)[i] = ((const uint*)ws)[i];
  for (int i = tid; i < 2048; i += 256)
    ((uint*)s_A)[i] = 0u;                                   // zero incl. pad rows 25-31,57-63

  // W -> per-lane B-fragments (register-resident for whole kernel)
  // B frag (16x16x32): col d = nt*16+(lr&15), k rows c = ks*32+(lr>>4)*8+j
  bf16x8 wfrag[2][4];
  #pragma unroll
  for (int ks = 0; ks < 2; ++ks)
    #pragma unroll
    for (int nt = 0; nt < 4; ++nt) {
      const int d = nt * 16 + (lr & 15);
      const int cb = ks * 32 + (lr >> 4) * 8;
      #pragma unroll
      for (int j = 0; j < 8; ++j)
        wfrag[ks][nt][j] = (short)f2bf(Wg[(cb + j) * 64 + d]);
    }

  // lane's accumulator-row geometry (C/D map: col=lane&15, row=(lane>>4)*4+reg)
  // block M-tile rows: 0..31 -> t-row 0 (w=row), 32..63 -> t-row 1 (w=row-32)
  float cmul[16], cadd[16];
  float ssum[16], ssq[16];
  #pragma unroll
  for (int k = 0; k < 16; ++k) { ssum[k] = 0.f; ssq[k] = 0.f; }
  if constexpr (PASS == 2) {
    #pragma unroll
    for (int nt = 0; nt < 4; ++nt)
      #pragma unroll
      for (int r = 0; r < 4; ++r) {
        int row = wid * 16 + (lr >> 4) * 4 + r;
        int w = row & 31;
        int d = nt * 16 + (lr & 15);
        int qq = (w < 25) ? (w * 64 + d) : 0;
        cmul[nt * 4 + r] = ws[4800 + qq];
        cadd[nt * 4 + r] = ws[6400 + qq];
      }
  }

  const int row_base = blockIdx.x * 16;
  const int n  = row_base >> 8;
  const int t0 = row_base & 255;

  if constexpr (PASS == 1) {
    for (int i = tid; i < 3200; i += 256) s_aux[i] = 0.f;
  }
  __syncthreads();

  for (int rp = 0; rp < 16; rp += 2) {
    const float* xrow = x0 + (size_t)(row_base + rp) * 1600;

    // ---- stage: read 2 raw rows, mask, cvt bf16, scatter into gathered A tile ----
    for (int i4 = tid; i4 < 800; i4 += 256) {
      float4 v = ((const float4*)xrow)[i4];
      int r2 = (i4 >= 400) ? 1 : 0;
      int p4 = (i4 - r2 * 400) * 4;          // raw float offset in row
      int wr = p4 >> 6, c0 = p4 & 63;
      if constexpr (PASS == 2)
        *(float4*)&s_raw[r2 * 1700 + wr * 68 + c0] = v;
      uint2 mm = *(const uint2*)&s_maskm[p4];
      float va[4] = {v.x, v.y, v.z, v.w};
      float ma[4] = {bf2f((ushort)(mm.x & 0xffff)), bf2f((ushort)(mm.x >> 16)),
                     bf2f((ushort)(mm.y & 0xffff)), bf2f((ushort)(mm.y >> 16))};
      int wbase = wr + 100 - c0;
      #pragma unroll
      for (int j = 0; j < 4; ++j) {
        int w = (wbase - j) % 25;
        int row = r2 * 32 + w;
        int byte = (row * 128 + (c0 + j) * 2) ^ ((w & 7) << 4);
        *(ushort*)((char*)s_A + byte) = f2bf(va[j] * ma[j]);
      }
    }
    __syncthreads();

    // ---- MFMA: per wave one 16-row M-tile x N=64, K=64 ----
    const int arow = wid * 16 + (lr & 15);
    bf16x8 afrag[2];
    #pragma unroll
    for (int ks = 0; ks < 2; ++ks) {
      int byte = (arow * 128 + ks * 64 + (lr >> 4) * 16) ^ ((arow & 7) << 4);
      afrag[ks] = *(const bf16x8*)((const char*)s_A + byte);
    }
    f32x4 acc[4];
    #pragma unroll
    for (int nt = 0; nt < 4; ++nt) {
      acc[nt] = (f32x4){0.f, 0.f, 0.f, 0.f};
      #pragma unroll
      for (int ks = 0; ks < 2; ++ks)
        acc[nt] = __builtin_amdgcn_mfma_f32_16x16x32_bf16(afrag[ks], wfrag[ks][nt], acc[nt], 0, 0, 0);
    }

    if constexpr (PASS == 1) {
      #pragma unroll
      for (int nt = 0; nt < 4; ++nt)
        #pragma unroll
        for (int r = 0; r < 4; ++r) {
          float y = acc[nt][r];
          ssum[nt * 4 + r] += y;
          ssq [nt * 4 + r]  = fmaf(y, y, ssq[nt * 4 + r]);
        }
      __syncthreads();           // A reads done before next scatter
    } else {
      // ---- epilogue: BN + residual + ReLU -> transpose tile ----
      #pragma unroll
      for (int nt = 0; nt < 4; ++nt)
        #pragma unroll
        for (int r = 0; r < 4; ++r) {
          int row = wid * 16 + (lr >> 4) * 4 + r;
          int r2 = row >> 5;
          int w  = row & 31;
          if (w < 25) {
            int d  = nt * 16 + (lr & 15);
            int wp = (w + d) % 25;
            float y = fmaf(acc[nt][r], cmul[nt * 4 + r], cadd[nt * 4 + r]);
            y += s_raw[r2 * 1700 + wp * 68 + d];
            s_aux[d * 50 + r2 * 25 + wp] = fmaxf(y, 0.f);
          }
        }
      __syncthreads();
      // ---- coalesced transposed store: 200B runs per d ----
      const size_t obase = (size_t)n * 409600 + (size_t)(t0 + rp) * 25;
      for (int i = tid; i < 3200; i += 256) {
        int d   = i / 50;
        int rem = i - d * 50;
        int r2  = rem / 25;
        int wp  = rem - r2 * 25;
        out[obase + (size_t)d * 6400 + r2 * 25 + wp] = s_aux[i];
      }
      __syncthreads();           // s_aux reads done before next epilogue writes
    }
  }

  if constexpr (PASS == 1) {
    // combine 2 contributors per column via LDS, then one global atomic per elem
    #pragma unroll
    for (int nt = 0; nt < 4; ++nt)
      #pragma unroll
      for (int r = 0; r < 4; ++r) {
        int row = wid * 16 + (lr >> 4) * 4 + r;
        int w = row & 31;
        if (w < 25) {
          int q = w * 64 + nt * 16 + (lr & 15);
          atomicAdd(&s_aux[q],        ssum[nt * 4 + r]);
          atomicAdd(&s_aux[1600 + q], ssq [nt * 4 + r]);
        }
      }
    __syncthreads();
    for (int i = tid; i < 3200; i += 256)
      atomicAdd(&ws[1600 + i], s_aux[i]);
  }
}

extern "C" void kernel_launch(void* const* d_in, const int* in_sizes, int n_in,
                              void* d_out, int out_size, void* d_ws, size_t ws_size,
                              hipStream_t stream) {
  const float* x0    = (const float*)d_in[0];
  const float* W     = (const float*)d_in[1];
  // d_in[2] Linear_bias: cancels in BN, ignored
  const float* mask  = (const float*)d_in[3];
  const float* gamma = (const float*)d_in[4];
  const float* beta  = (const float*)d_in[5];
  // d_in[6], d_in[7] shift indices: computed analytically, ignored
  float* ws  = (float*)d_ws;
  float* out = (float*)d_out;

  k_prep    <<<13,   256, 0, stream>>>(mask, ws);
  k_main<1> <<<1024, 256, 0, stream>>>(x0, W, ws, out);
  k_finalize<<<7,    256, 0, stream>>>(gamma, beta, ws);
  k_main<2> <<<1024, 256, 0, stream>>>(x0, W, ws, out);
}